// Round 9
// baseline (260.050 us; speedup 1.0000x reference)
//
#include <hip/hip_runtime.h>
#include <hip/hip_fp16.h>
#include <cstdint>
#include <cstddef>

// Problem constants (fixed by reference)
#define NB      64      // batch
#define NBITS   4096
#define HD      64      // hidden
#define IN_DIM  4098
#define LMAXT   320
#define SEQ_STRIDE 336  // padded seq row (>= LMAX+2, mult of 16)
#define NTILE   257     // col tiles of 16 (4112 padded cols)
#define LOG2E   1.44269504088896340f
#define CSPLIT  8       // column-split waves per k_proj block

// Workspace layout (bytes), all 256-aligned
static constexpr size_t SEQ_OFF   = 0;                               // 86016
static constexpr size_t STEPS_OFF = 86016;                           // 256
static constexpr size_t LOSS_OFF  = 86272;                           // 256
static constexpr size_t XB_OFF    = 86528;                           // 64*320*64*2 = 2621440
static constexpr size_t WB_OFF    = XB_OFF + 2621440;                // 257*1024*2 = 526336
static constexpr size_t BO_OFF    = WB_OFF + 526336;                 // 4112*4

typedef __bf16    bf16x8 __attribute__((ext_vector_type(8)));
typedef float     f32x4  __attribute__((ext_vector_type(4)));
typedef _Float16  h2     __attribute__((ext_vector_type(2)));

// glibc's math.h macro-expands a declaration named __exp2f -> do NOT use that
// identifier; go straight to the HW builtin (v_exp_f32).
__device__ __forceinline__ float ex2(float x) {
#if __has_builtin(__builtin_amdgcn_exp2f)
  return __builtin_amdgcn_exp2f(x);
#else
  return __expf(x * 0.6931471805599453f);
#endif
}
// raw v_rcp_f32 (~1 ulp): keeps the gate chain off the slow exact-div sequence
__device__ __forceinline__ float frcp(float x) {
#if __has_builtin(__builtin_amdgcn_rcpf)
  return __builtin_amdgcn_rcpf(x);
#else
  return 1.f / x;
#endif
}
// swap adjacent lanes (lane ^ 1) via DPP quad_perm [1,0,3,2] -- pure VALU.
__device__ __forceinline__ float swap1(float x) {
#if __has_builtin(__builtin_amdgcn_mov_dpp)
  return __int_as_float(
      __builtin_amdgcn_mov_dpp(__float_as_int(x), 0xB1, 0xF, 0xF, true));
#else
  return __shfl_xor(x, 1, 64);
#endif
}
// pack two f32 -> h2 via v_cvt_pkrtz_f16_f32 (builtin returns __fp16x2;
// bit_cast to our _Float16-based h2 -- layouts are identical)
__device__ __forceinline__ h2 pk2(float lo, float hi) {
  return __builtin_bit_cast(h2, __builtin_amdgcn_cvt_pkrtz(lo, hi));
}

__device__ __forceinline__ unsigned short f2bf(float f) {
  unsigned u = __float_as_uint(f);
  unsigned r = u + 0x7FFFu + ((u >> 16) & 1u);   // RNE
  return (unsigned short)(r >> 16);
}
__device__ __forceinline__ float bf2f(unsigned short u) {
  return __uint_as_float((unsigned)u << 16);
}
__device__ __forceinline__ bf16x8 ldb8(const unsigned short* p) {
  return *(const bf16x8*)p;
}
__device__ __forceinline__ void wave_lds_fence() {
  __asm__ __volatile__("s_waitcnt lgkmcnt(0)" ::: "memory");
}

// ---------------------------------------------------------------------------
// Kernel A: compaction. Stage 1 builds a 4096-bit LDS mask from a coalesced
// row read; stage 2 scans in perm order against LDS (no HBM gather).
// ---------------------------------------------------------------------------
__global__ __launch_bounds__(64) void k_setup(
    const float* __restrict__ true_fp, const int* __restrict__ perm,
    int* __restrict__ seq, int* __restrict__ steps,
    float* __restrict__ loss_accum) {
  const int b = blockIdx.x;
  const int j = threadIdx.x;
  if (b == 0 && j == 0) *loss_accum = 0.f;
  __shared__ unsigned long long bits[64];
  const float* row = true_fp + (size_t)b * NBITS;

  {
    const float4* rv = (const float4*)(row + j * 64);
    unsigned long long w = 0ull;
#pragma unroll
    for (int i = 0; i < 16; ++i) {
      const float4 v = rv[i];
      w |= (unsigned long long)(v.x > 0.f) << (4 * i + 0);
      w |= (unsigned long long)(v.y > 0.f) << (4 * i + 1);
      w |= (unsigned long long)(v.z > 0.f) << (4 * i + 2);
      w |= (unsigned long long)(v.w > 0.f) << (4 * i + 3);
    }
    bits[j] = w;
  }
  wave_lds_fence();

  int* srow = seq + b * SEQ_STRIDE;
  int base = 0;
  for (int c0 = 0; c0 < IN_DIM; c0 += 64) {
    const int col = c0 + j;
    bool pred = false;
    if (col < IN_DIM) {
      if (col == 0 || col == IN_DIM - 1) pred = true;
      else {
        const int p = perm[col - 1];
        pred = (bits[p >> 6] >> (p & 63)) & 1ull;
      }
    }
    const unsigned long long mask = __ballot(pred);
    const int prefix = __popcll(mask & ((1ull << j) - 1ull));
    const int idx = base + prefix;
    if (pred && idx <= LMAXT) srow[idx] = col;
    base += __popcll(mask);
  }
  const int cap = (base <= LMAXT + 1) ? base : (LMAXT + 1);
  for (int i = cap + j; i < SEQ_STRIDE; i += 64) srow[i] = 0;
  if (j == 0) {
    int s = base - 1;
    if (s > LMAXT) s = LMAXT;
    steps[b] = s;
  }
}

// ---------------------------------------------------------------------------
// Kernel A2: bf16 fragment-major W tiles + pre-scaled shifted bias
// bo2[col] = (b_out[col]-30)*log2(e); pad -1e30. Coalesced W_out reads.
// ---------------------------------------------------------------------------
__global__ __launch_bounds__(256) void k_prep(
    const float* __restrict__ W_out, const float* __restrict__ b_out,
    unsigned short* __restrict__ Wb, float* __restrict__ bo2) {
  const int c = blockIdx.x;            // 0..256
  const int t = threadIdx.x;
  const int m = t & 15;                // col within tile
  const int col = c * 16 + m;
  const bool cok = col < IN_DIM;
#pragma unroll
  for (int kp = 0; kp < 4; ++kp) {
    const int k = kp * 16 + (t >> 4);
    const float v = cok ? W_out[(size_t)k * IN_DIM + col] : 0.f;
    Wb[c * 1024 + m * 64 + k] = f2bf(v);
  }
  if (t < 16) {
    const int cc = c * 16 + t;
    bo2[c * 16 + t] = (cc < IN_DIM) ? (b_out[cc] - 30.f) * LOG2E : -1e30f;
  }
}

// ---------------------------------------------------------------------------
// Kernel B: GRU recurrence. ONE WAVE per batch row, ZERO LDS in the step
// loop. R7 showed ~1000cyc/step dominated by the LDS h-broadcast round trip
// (write+fence+32 ds_read on a lone wave). Here: h broadcast via registers
// -- DPP pair-swap + v_cvt_pkrtz pack, then 32x v_readlane into SGPRs;
// v_pk_fma_f16 reads h directly from SGPRs (1 sgpr operand/instr is legal).
// Depth-4 named W_ih prefetch covers HBM-miss latency of the shorter step.
// ---------------------------------------------------------------------------
#define W_DEF(i) h2 wr##i, wz##i, wn##i;
#define W_INIT(i) {                                                  \
    const float* w0_ = W_hh + (size_t)(2 * (i)) * 192;               \
    const float* w1_ = W_hh + (size_t)(2 * (i) + 1) * 192;           \
    wr##i[0] = (_Float16)w0_[g];       wr##i[1] = (_Float16)w1_[g];  \
    wz##i[0] = (_Float16)w0_[64 + g];  wz##i[1] = (_Float16)w1_[64 + g]; \
    wn##i[0] = (_Float16)w0_[128 + g]; wn##i[1] = (_Float16)w1_[128 + g]; }

// broadcast: pull packed h2 pair k (lane 2k) into a wave-uniform value
#define RL(k) const h2 hv##k = __builtin_bit_cast(                   \
    h2, __builtin_amdgcn_readlane(__builtin_bit_cast(int, hpk), 2 * (k)));
#define W_FMA(i, s) { ar##s += hv##i * wr##i;                        \
                      az##s += hv##i * wz##i;                        \
                      an##s += hv##i * wn##i; }

__global__ __launch_bounds__(64)
__attribute__((amdgpu_waves_per_eu(1, 1)))
void k_gru(
    const float* __restrict__ embeds,
    const float* __restrict__ W_ih, const float* __restrict__ b_ih,
    const float* __restrict__ W_hh, const float* __restrict__ b_hh,
    const int* __restrict__ seq, const int* __restrict__ steps,
    unsigned short* __restrict__ Xb) {
  const int b = blockIdx.x;
  const int g = threadIdx.x;   // 0..63

  __shared__ int seqL[LMAXT + 2];
  for (int i = g; i < LMAXT + 2; i += 64) seqL[i] = seq[b * SEQ_STRIDE + i];
  wave_lds_fence();

  // 96 named h2 registers: W_hh columns for unit g over k-pairs
  W_DEF(0)  W_DEF(1)  W_DEF(2)  W_DEF(3)  W_DEF(4)  W_DEF(5)  W_DEF(6)  W_DEF(7)
  W_DEF(8)  W_DEF(9)  W_DEF(10) W_DEF(11) W_DEF(12) W_DEF(13) W_DEF(14) W_DEF(15)
  W_DEF(16) W_DEF(17) W_DEF(18) W_DEF(19) W_DEF(20) W_DEF(21) W_DEF(22) W_DEF(23)
  W_DEF(24) W_DEF(25) W_DEF(26) W_DEF(27) W_DEF(28) W_DEF(29) W_DEF(30) W_DEF(31)
  W_INIT(0)  W_INIT(1)  W_INIT(2)  W_INIT(3)  W_INIT(4)  W_INIT(5)  W_INIT(6)  W_INIT(7)
  W_INIT(8)  W_INIT(9)  W_INIT(10) W_INIT(11) W_INIT(12) W_INIT(13) W_INIT(14) W_INIT(15)
  W_INIT(16) W_INIT(17) W_INIT(18) W_INIT(19) W_INIT(20) W_INIT(21) W_INIT(22) W_INIT(23)
  W_INIT(24) W_INIT(25) W_INIT(26) W_INIT(27) W_INIT(28) W_INIT(29) W_INIT(30) W_INIT(31)

  const float bhn = b_hh[128 + g];
  const float br  = b_ih[g] + b_hh[g];              // folded r-gate bias
  const float bz  = b_ih[64 + g] + b_hh[64 + g];    // folded z-gate bias
  const float bn  = b_ih[128 + g];
  const int nst = steps[b];

  float hself = embeds[b * HD + g];
  // even lane 2k holds packed (h[2k], h[2k+1])
  h2 hpk = pk2(hself, swap1(hself));

  unsigned short* xrow = Xb + (size_t)b * LMAXT * HD + g;

  // depth-4 named prefetch slots for this thread's 3 W_ih elements
  float p0r, p0z, p0n, p1r, p1z, p1n, p2r, p2z, p2n, p3r, p3z, p3n;
  {
    const float* r0 = W_ih + (size_t)seqL[0] * 192;
    p0r = r0[g]; p0z = r0[64 + g]; p0n = r0[128 + g];
    const float* r1 = W_ih + (size_t)seqL[1] * 192;
    p1r = r1[g]; p1z = r1[64 + g]; p1n = r1[128 + g];
    const float* r2 = W_ih + (size_t)seqL[2] * 192;
    p2r = r2[g]; p2z = r2[64 + g]; p2n = r2[128 + g];
    const float* r3 = W_ih + (size_t)seqL[3] * 192;
    p3r = r3[g]; p3z = r3[64 + g]; p3n = r3[128 + g];
  }

  h2 hz; hz[0] = (_Float16)0.f; hz[1] = (_Float16)0.f;

#define GSTEP(u) {                                                        \
    RL(0)  RL(1)  RL(2)  RL(3)  RL(4)  RL(5)  RL(6)  RL(7)                \
    RL(8)  RL(9)  RL(10) RL(11) RL(12) RL(13) RL(14) RL(15)               \
    RL(16) RL(17) RL(18) RL(19) RL(20) RL(21) RL(22) RL(23)               \
    RL(24) RL(25) RL(26) RL(27) RL(28) RL(29) RL(30) RL(31)               \
    h2 ar0 = hz, ar1 = hz, az0 = hz, az1 = hz, an0 = hz, an1 = hz;        \
    W_FMA(0, 0)  W_FMA(1, 1)  W_FMA(2, 0)  W_FMA(3, 1)                    \
    W_FMA(4, 0)  W_FMA(5, 1)  W_FMA(6, 0)  W_FMA(7, 1)                    \
    W_FMA(8, 0)  W_FMA(9, 1)  W_FMA(10, 0) W_FMA(11, 1)                   \
    W_FMA(12, 0) W_FMA(13, 1) W_FMA(14, 0) W_FMA(15, 1)                   \
    W_FMA(16, 0) W_FMA(17, 1) W_FMA(18, 0) W_FMA(19, 1)                   \
    W_FMA(20, 0) W_FMA(21, 1) W_FMA(22, 0) W_FMA(23, 1)                   \
    W_FMA(24, 0) W_FMA(25, 1) W_FMA(26, 0) W_FMA(27, 1)                   \
    W_FMA(28, 0) W_FMA(29, 1) W_FMA(30, 0) W_FMA(31, 1)                   \
    const float sr = ((float)ar0[0] + (float)ar0[1]) +                    \
                     ((float)ar1[0] + (float)ar1[1]);                     \
    const float sz = ((float)az0[0] + (float)az0[1]) +                    \
                     ((float)az1[0] + (float)az1[1]);                     \
    const float sn = ((float)an0[0] + (float)an0[1]) +                    \
                     ((float)an1[0] + (float)an1[1]);                     \
    const float ar = sr + br + p##u##r;                                   \
    const float az = sz + bz + p##u##z;                                   \
    const float ghn = sn + bhn;                                           \
    const float rr = frcp(1.f + ex2(ar * -LOG2E));                        \
    const float zz = frcp(1.f + ex2(az * -LOG2E));                        \
    const float nx = (p##u##n + bn) + rr * ghn;                           \
    const float th = 1.f - 2.f * frcp(1.f + ex2(nx * (2.f * LOG2E)));     \
    const float hn = th + zz * (hself - th);                              \
    hself = hn;                                                           \
    hpk = pk2(hn, swap1(hn));                                             \
    if (t + (u) < nst) xrow[(size_t)(t + (u)) * HD] = f2bf(hn);           \
    int nt_ = t + (u) + 4; nt_ = (nt_ <= LMAXT + 1) ? nt_ : (LMAXT + 1);  \
    const float* rw_ = W_ih + (size_t)seqL[nt_] * 192;                    \
    p##u##r = rw_[g]; p##u##z = rw_[64 + g]; p##u##n = rw_[128 + g]; }

  const int ngroups = (nst + 3) >> 2;
  for (int tg = 0; tg < ngroups; ++tg) {
    const int t = tg * 4;
    GSTEP(0)
    GSTEP(1)
    GSTEP(2)
    GSTEP(3)
  }
#undef GSTEP

  // zero-fill padded rows (ws is re-poisoned before every call)
  for (int i = nst * HD + g; i < LMAXT * HD; i += 64)
    Xb[(size_t)b * (LMAXT * HD) + i] = 0;
}

// ---------------------------------------------------------------------------
// Kernel C: MFMA bf16 fused projection + logsumexp + NLL.
// Block = 512 threads = 8 waves sharing one (b, 32-row chunk); waves split
// the 257 column tiles (33 each -> 66 KB Wb stream per wave). Partial exp
// sums merge via LDS. Grid 640 blocks -> 20 waves/CU.
// ---------------------------------------------------------------------------
__global__ __launch_bounds__(512) void k_proj(
    const unsigned short* __restrict__ Xb,
    const unsigned short* __restrict__ Wb,
    const float* __restrict__ bo2,
    const int* __restrict__ seq, const int* __restrict__ steps,
    const float* __restrict__ b_out,
    float* __restrict__ loss_accum) {
  const int l  = threadIdx.x & 63;
  const int wv = threadIdx.x >> 6;         // 0..7 column-split wave id
  const int b  = blockIdx.x / 10;
  const int t0 = (blockIdx.x % 10) * 32;
  const int nst = steps[b];
  const bool active = (t0 < nst);          // block-uniform

  __shared__ float spart[CSPLIT][32];

  if (active) {
    const int lm = l & 15;
    const int q  = l >> 4;

    const unsigned short* xp0 = Xb + ((size_t)b * LMAXT + t0 + lm) * HD + q * 8;
    const bf16x8 a00 = ldb8(xp0);
    const bf16x8 a01 = ldb8(xp0 + 32);
    const bf16x8 a10 = ldb8(xp0 + 16 * HD);
    const bf16x8 a11 = ldb8(xp0 + 16 * HD + 32);

    float s[8];
#pragma unroll
    for (int i = 0; i < 8; ++i) s[i] = 0.f;

    const int ct0 = wv * 33;
    const int ct1 = (ct0 + 33 < NTILE) ? (ct0 + 33) : NTILE;   // wave 7: 26

    const unsigned short* wp = Wb + lm * 64 + q * 8;
    const float* bop = bo2 + lm;

    bf16x8 b0 = ldb8(wp + (size_t)ct0 * 1024);
    bf16x8 b1 = ldb8(wp + (size_t)ct0 * 1024 + 32);
    float  bo = bop[ct0 * 16];
    for (int ct = ct0; ct < ct1; ++ct) {
      bf16x8 nb0, nb1; float nbo;
      if (ct + 1 < ct1) {
        const unsigned short* wpn = wp + (size_t)(ct + 1) * 1024;
        nb0 = ldb8(wpn); nb1 = ldb8(wpn + 32); nbo = bop[(ct + 1) * 16];
      }
      f32x4 acc0 = {0.f, 0.f, 0.f, 0.f};
      f32x4 acc1 = {0.f, 0.f, 0.f, 0.f};
      acc0 = __builtin_amdgcn_mfma_f32_16x16x32_bf16(a00, b0, acc0, 0, 0, 0);
      acc0 = __builtin_amdgcn_mfma_f32_16x16x32_bf16(a01, b1, acc0, 0, 0, 0);
      acc1 = __builtin_amdgcn_mfma_f32_16x16x32_bf16(a10, b0, acc1, 0, 0, 0);
      acc1 = __builtin_amdgcn_mfma_f32_16x16x32_bf16(a11, b1, acc1, 0, 0, 0);
#pragma unroll
      for (int i = 0; i < 4; ++i) {
        s[i]     += ex2(fmaf(acc0[i], LOG2E, bo));
        s[4 + i] += ex2(fmaf(acc1[i], LOG2E, bo));
      }
      if (ct + 1 < ct1) { b0 = nb0; b1 = nb1; bo = nbo; }
    }

    // reduce across the 16 lanes (lm) sharing each row
#pragma unroll
    for (int m = 1; m < 16; m <<= 1) {
#pragma unroll
      for (int i = 0; i < 8; ++i) s[i] += __shfl_xor(s[i], m, 64);
    }
    // D-layout: lane q*16 holds rows q*4+i (tile0) / 16+q*4+i (tile1)
    if (lm == 0) {
#pragma unroll
      for (int i = 0; i < 4; ++i) {
        spart[wv][q * 4 + i]      = s[i];
        spart[wv][16 + q * 4 + i] = s[4 + i];
      }
    }
  }
  __syncthreads();

  float nll = 0.f;
  if (active && threadIdx.x < 32) {
    const int t = t0 + threadIdx.x;
    if (t < nst) {
      float ssum = 0.f;
#pragma unroll
      for (int c = 0; c < CSPLIT; ++c) ssum += spart[c][threadIdx.x];
      const int col = seq[b * SEQ_STRIDE + t + 1];
      // target logit from the SAME bf16 operands (consistent cancellation)
      const unsigned short* xr = Xb + ((size_t)b * LMAXT + t) * HD;
      const unsigned short* wc = Wb + (size_t)(col >> 4) * 1024 + (col & 15) * 64;
      float tl = b_out[col];
#pragma unroll 16
      for (int k = 0; k < 64; ++k)
        tl = fmaf(bf2f(xr[k]), bf2f(wc[k]), tl);
      nll = (30.f + __logf(ssum)) - tl;
    }
  }
  if (threadIdx.x < 64) {
#pragma unroll
    for (int off = 32; off; off >>= 1) nll += __shfl_down(nll, off, 64);
    if (threadIdx.x == 0) atomicAdd(loss_accum, nll);
  }
}

// ---------------------------------------------------------------------------
// Kernel D: finalize (loss_sum / count).
// ---------------------------------------------------------------------------
__global__ void k_final(const float* __restrict__ loss_accum,
                        const int* __restrict__ steps,
                        float* __restrict__ out) {
  if (threadIdx.x == 0 && blockIdx.x == 0) {
    int cnt = 0;
    for (int i = 0; i < NB; ++i) cnt += steps[i];
    out[0] = loss_accum[0] / (float)cnt;
  }
}

// ---------------------------------------------------------------------------
extern "C" void kernel_launch(void* const* d_in, const int* in_sizes, int n_in,
                              void* d_out, int out_size, void* d_ws,
                              size_t ws_size, hipStream_t stream) {
  const float* embeds  = (const float*)d_in[0];
  const float* true_fp = (const float*)d_in[1];
  const int*   perm    = (const int*)d_in[5];
  const float* W_ih    = (const float*)d_in[6];
  const float* b_ih    = (const float*)d_in[7];
  const float* W_hh    = (const float*)d_in[8];
  const float* b_hh    = (const float*)d_in[9];
  const float* W_out   = (const float*)d_in[10];
  const float* b_out   = (const float*)d_in[11];

  char*  ws     = (char*)d_ws;
  int*   seq    = (int*)(ws + SEQ_OFF);
  int*   steps  = (int*)(ws + STEPS_OFF);
  float* loss   = (float*)(ws + LOSS_OFF);
  unsigned short* Xb = (unsigned short*)(ws + XB_OFF);
  unsigned short* Wb = (unsigned short*)(ws + WB_OFF);
  float* bo2    = (float*)(ws + BO_OFF);
  float* out    = (float*)d_out;

  k_setup<<<NB, 64, 0, stream>>>(true_fp, perm, seq, steps, loss);
  k_prep<<<NTILE, 256, 0, stream>>>(W_out, b_out, Wb, bo2);
  k_gru<<<NB, 64, 0, stream>>>(embeds, W_ih, b_ih, W_hh, b_hh, seq, steps, Xb);
  k_proj<<<640, 512, 0, stream>>>(Xb, Wb, bo2, seq, steps, b_out, loss);
  k_final<<<1, 64, 0, stream>>>(loss, steps, out);
}

// Round 10
// 241.019 us; speedup vs baseline: 1.0790x; 1.0790x over previous
//
#include <hip/hip_runtime.h>
#include <hip/hip_fp16.h>
#include <cstdint>
#include <cstddef>

// Problem constants (fixed by reference)
#define NB      64      // batch
#define NBITS   4096
#define HD      64      // hidden
#define IN_DIM  4098
#define LMAXT   320
#define SEQ_STRIDE 336  // padded seq row (>= LMAX+2, mult of 16)
#define NTILE   257     // col tiles of 16 (4112 padded cols)
#define LOG2E   1.44269504088896340f
#define CSPLIT  8       // column-split waves per k_proj block

// Workspace layout (bytes), all 256-aligned
static constexpr size_t SEQ_OFF   = 0;                               // 86016
static constexpr size_t STEPS_OFF = 86016;                           // 256
static constexpr size_t LOSS_OFF  = 86272;                           // 256
static constexpr size_t XB_OFF    = 86528;                           // 64*320*64*2 = 2621440
static constexpr size_t WB_OFF    = XB_OFF + 2621440;                // 257*1024*2 = 526336
static constexpr size_t BO_OFF    = WB_OFF + 526336;                 // 4112*4

typedef __bf16    bf16x8 __attribute__((ext_vector_type(8)));
typedef float     f32x4  __attribute__((ext_vector_type(4)));
typedef _Float16  h2     __attribute__((ext_vector_type(2)));
typedef _Float16  h8     __attribute__((ext_vector_type(8)));

#if __has_builtin(__builtin_amdgcn_fdot2)
#define FDOT2(a, b, c) __builtin_amdgcn_fdot2((a), (b), (c), false)
#else
#define FDOT2(a, b, c) fmaf((float)(a)[0], (float)(b)[0], \
                        fmaf((float)(a)[1], (float)(b)[1], (c)))
#endif

// glibc's math.h macro-expands a declaration named __exp2f -> do NOT use that
// identifier; go straight to the HW builtin (v_exp_f32).
__device__ __forceinline__ float ex2(float x) {
#if __has_builtin(__builtin_amdgcn_exp2f)
  return __builtin_amdgcn_exp2f(x);
#else
  return __expf(x * 0.6931471805599453f);
#endif
}
// raw v_rcp_f32 (~1 ulp): keeps the gate chain off the slow exact-div sequence
__device__ __forceinline__ float frcp(float x) {
#if __has_builtin(__builtin_amdgcn_rcpf)
  return __builtin_amdgcn_rcpf(x);
#else
  return 1.f / x;
#endif
}

__device__ __forceinline__ unsigned short f2bf(float f) {
  unsigned u = __float_as_uint(f);
  unsigned r = u + 0x7FFFu + ((u >> 16) & 1u);   // RNE
  return (unsigned short)(r >> 16);
}
__device__ __forceinline__ float bf2f(unsigned short u) {
  return __uint_as_float((unsigned)u << 16);
}
__device__ __forceinline__ bf16x8 ldb8(const unsigned short* p) {
  return *(const bf16x8*)p;
}
__device__ __forceinline__ void wave_lds_fence() {
  __asm__ __volatile__("s_waitcnt lgkmcnt(0)" ::: "memory");
}

// ---------------------------------------------------------------------------
// Kernel A: compaction. Stage 1 builds a 4096-bit LDS mask from a coalesced
// row read; stage 2 scans in perm order against LDS (no HBM gather).
// ---------------------------------------------------------------------------
__global__ __launch_bounds__(64) void k_setup(
    const float* __restrict__ true_fp, const int* __restrict__ perm,
    int* __restrict__ seq, int* __restrict__ steps,
    float* __restrict__ loss_accum) {
  const int b = blockIdx.x;
  const int j = threadIdx.x;
  if (b == 0 && j == 0) *loss_accum = 0.f;
  __shared__ unsigned long long bits[64];
  const float* row = true_fp + (size_t)b * NBITS;

  {
    const float4* rv = (const float4*)(row + j * 64);
    unsigned long long w = 0ull;
#pragma unroll
    for (int i = 0; i < 16; ++i) {
      const float4 v = rv[i];
      w |= (unsigned long long)(v.x > 0.f) << (4 * i + 0);
      w |= (unsigned long long)(v.y > 0.f) << (4 * i + 1);
      w |= (unsigned long long)(v.z > 0.f) << (4 * i + 2);
      w |= (unsigned long long)(v.w > 0.f) << (4 * i + 3);
    }
    bits[j] = w;
  }
  wave_lds_fence();

  int* srow = seq + b * SEQ_STRIDE;
  int base = 0;
  for (int c0 = 0; c0 < IN_DIM; c0 += 64) {
    const int col = c0 + j;
    bool pred = false;
    if (col < IN_DIM) {
      if (col == 0 || col == IN_DIM - 1) pred = true;
      else {
        const int p = perm[col - 1];
        pred = (bits[p >> 6] >> (p & 63)) & 1ull;
      }
    }
    const unsigned long long mask = __ballot(pred);
    const int prefix = __popcll(mask & ((1ull << j) - 1ull));
    const int idx = base + prefix;
    if (pred && idx <= LMAXT) srow[idx] = col;
    base += __popcll(mask);
  }
  const int cap = (base <= LMAXT + 1) ? base : (LMAXT + 1);
  for (int i = cap + j; i < SEQ_STRIDE; i += 64) srow[i] = 0;
  if (j == 0) {
    int s = base - 1;
    if (s > LMAXT) s = LMAXT;
    steps[b] = s;
  }
}

// ---------------------------------------------------------------------------
// Kernel A2: bf16 fragment-major W tiles + pre-scaled shifted bias
// bo2[col] = (b_out[col]-30)*log2(e); pad -1e30. Coalesced W_out reads.
// ---------------------------------------------------------------------------
__global__ __launch_bounds__(256) void k_prep(
    const float* __restrict__ W_out, const float* __restrict__ b_out,
    unsigned short* __restrict__ Wb, float* __restrict__ bo2) {
  const int c = blockIdx.x;            // 0..256
  const int t = threadIdx.x;
  const int m = t & 15;                // col within tile
  const int col = c * 16 + m;
  const bool cok = col < IN_DIM;
#pragma unroll
  for (int kp = 0; kp < 4; ++kp) {
    const int k = kp * 16 + (t >> 4);
    const float v = cok ? W_out[(size_t)k * IN_DIM + col] : 0.f;
    Wb[c * 1024 + m * 64 + k] = f2bf(v);
  }
  if (t < 16) {
    const int cc = c * 16 + t;
    bo2[c * 16 + t] = (cc < IN_DIM) ? (b_out[cc] - 30.f) * LOG2E : -1e30f;
  }
}

// ---------------------------------------------------------------------------
// Kernel B: GRU recurrence. ONE WAVE per batch row.
// R9 post-mortem: per-step time ~= instr_count x ~4cyc single-wave issue
// cadence (three different h-broadcasts all ~101us). So: MINIMIZE the
// instruction count per step. h broadcast = 1 ds_write_b16 + 8 ds_read_b128
// (h2 extracts are free sub-register refs); dots = 96 v_dot2_f32_f16 (f32
// accumulate, no convert tail); store unconditional (tail zero-fill
// overwrites padded rows); gates via exp2+rcp. ~145 instrs/step vs R9's 175.
// ---------------------------------------------------------------------------
#define W_DEF(i) h2 wr##i, wz##i, wn##i;
#define W_INIT(i) {                                                  \
    const float* w0_ = W_hh + (size_t)(2 * (i)) * 192;               \
    const float* w1_ = W_hh + (size_t)(2 * (i) + 1) * 192;           \
    wr##i[0] = (_Float16)w0_[g];       wr##i[1] = (_Float16)w1_[g];  \
    wz##i[0] = (_Float16)w0_[64 + g];  wz##i[1] = (_Float16)w1_[64 + g]; \
    wn##i[0] = (_Float16)w0_[128 + g]; wn##i[1] = (_Float16)w1_[128 + g]; }

// one h8 (4 VGPRs) -> 4 h2 sub-register views + 12 dot2 (i = h8 index)
#define DOT8(i) {                                                         \
    const h8 v_ = hp8[i];                                                 \
    const h2 e0_ = __builtin_shufflevector(v_, v_, 0, 1);                 \
    const h2 e1_ = __builtin_shufflevector(v_, v_, 2, 3);                 \
    const h2 e2_ = __builtin_shufflevector(v_, v_, 4, 5);                 \
    const h2 e3_ = __builtin_shufflevector(v_, v_, 6, 7);                 \
    sr0 = FDOT2(e0_, wr##i##_0, sr0);  sr1 = FDOT2(e1_, wr##i##_1, sr1);  \
    sr0 = FDOT2(e2_, wr##i##_2, sr0);  sr1 = FDOT2(e3_, wr##i##_3, sr1);  \
    sz0 = FDOT2(e0_, wz##i##_0, sz0);  sz1 = FDOT2(e1_, wz##i##_1, sz1);  \
    sz0 = FDOT2(e2_, wz##i##_2, sz0);  sz1 = FDOT2(e3_, wz##i##_3, sz1);  \
    sn0 = FDOT2(e0_, wn##i##_0, sn0);  sn1 = FDOT2(e1_, wn##i##_1, sn1);  \
    sn0 = FDOT2(e2_, wn##i##_2, sn0);  sn1 = FDOT2(e3_, wn##i##_3, sn1); }

// alias groups of 4 k-pair registers to h8-index naming (i8 = 4*i2_base)
#define W_ALIAS(i8, a, b, c, d)                                           \
  const h2 wr##i8##_0 = wr##a, wr##i8##_1 = wr##b,                        \
           wr##i8##_2 = wr##c, wr##i8##_3 = wr##d;                        \
  const h2 wz##i8##_0 = wz##a, wz##i8##_1 = wz##b,                        \
           wz##i8##_2 = wz##c, wz##i8##_3 = wz##d;                        \
  const h2 wn##i8##_0 = wn##a, wn##i8##_1 = wn##b,                        \
           wn##i8##_2 = wn##c, wn##i8##_3 = wn##d;

__global__ __launch_bounds__(64)
__attribute__((amdgpu_waves_per_eu(1, 1)))
void k_gru(
    const float* __restrict__ embeds,
    const float* __restrict__ W_ih, const float* __restrict__ b_ih,
    const float* __restrict__ W_hh, const float* __restrict__ b_hh,
    const int* __restrict__ seq, const int* __restrict__ steps,
    unsigned short* __restrict__ Xb) {
  const int b = blockIdx.x;
  const int g = threadIdx.x;   // 0..63

  __shared__ __align__(16) _Float16 hl[HD];
  __shared__ int seqL[LMAXT + 2];
  for (int i = g; i < LMAXT + 2; i += 64) seqL[i] = seq[b * SEQ_STRIDE + i];

  // 96 named h2 registers: W_hh columns for unit g over k-pairs
  W_DEF(0)  W_DEF(1)  W_DEF(2)  W_DEF(3)  W_DEF(4)  W_DEF(5)  W_DEF(6)  W_DEF(7)
  W_DEF(8)  W_DEF(9)  W_DEF(10) W_DEF(11) W_DEF(12) W_DEF(13) W_DEF(14) W_DEF(15)
  W_DEF(16) W_DEF(17) W_DEF(18) W_DEF(19) W_DEF(20) W_DEF(21) W_DEF(22) W_DEF(23)
  W_DEF(24) W_DEF(25) W_DEF(26) W_DEF(27) W_DEF(28) W_DEF(29) W_DEF(30) W_DEF(31)
  W_INIT(0)  W_INIT(1)  W_INIT(2)  W_INIT(3)  W_INIT(4)  W_INIT(5)  W_INIT(6)  W_INIT(7)
  W_INIT(8)  W_INIT(9)  W_INIT(10) W_INIT(11) W_INIT(12) W_INIT(13) W_INIT(14) W_INIT(15)
  W_INIT(16) W_INIT(17) W_INIT(18) W_INIT(19) W_INIT(20) W_INIT(21) W_INIT(22) W_INIT(23)
  W_INIT(24) W_INIT(25) W_INIT(26) W_INIT(27) W_INIT(28) W_INIT(29) W_INIT(30) W_INIT(31)
  W_ALIAS(0, 0, 1, 2, 3)     W_ALIAS(1, 4, 5, 6, 7)
  W_ALIAS(2, 8, 9, 10, 11)   W_ALIAS(3, 12, 13, 14, 15)
  W_ALIAS(4, 16, 17, 18, 19) W_ALIAS(5, 20, 21, 22, 23)
  W_ALIAS(6, 24, 25, 26, 27) W_ALIAS(7, 28, 29, 30, 31)

  const float bhn = b_hh[128 + g];
  const float br  = b_ih[g] + b_hh[g];              // folded r-gate bias
  const float bz  = b_ih[64 + g] + b_hh[64 + g];    // folded z-gate bias
  const float bn  = b_ih[128 + g];
  const int nst = steps[b];

  float hself = embeds[b * HD + g];
  hl[g] = (_Float16)hself;

  unsigned short* xptr = Xb + (size_t)b * LMAXT * HD + g;

  // depth-4 named prefetch slots for this thread's 3 W_ih elements
  float p0r, p0z, p0n, p1r, p1z, p1n, p2r, p2z, p2n, p3r, p3z, p3n;
  {
    const float* r0 = W_ih + (size_t)seqL[0] * 192;
    p0r = r0[g]; p0z = r0[64 + g]; p0n = r0[128 + g];
    const float* r1 = W_ih + (size_t)seqL[1] * 192;
    p1r = r1[g]; p1z = r1[64 + g]; p1n = r1[128 + g];
    const float* r2 = W_ih + (size_t)seqL[2] * 192;
    p2r = r2[g]; p2z = r2[64 + g]; p2n = r2[128 + g];
    const float* r3 = W_ih + (size_t)seqL[3] * 192;
    p3r = r3[g]; p3z = r3[64 + g]; p3n = r3[128 + g];
  }

#define GSTEP(u) {                                                        \
    int nt_ = t + (u) + 4; nt_ = (nt_ <= LMAXT + 1) ? nt_ : (LMAXT + 1);  \
    const int sidx_ = seqL[nt_];                                          \
    const h8* hp8 = (const h8*)hl;                                        \
    float sr0 = 0.f, sr1 = 0.f, sz0 = 0.f, sz1 = 0.f, sn0 = 0.f, sn1 = 0.f; \
    DOT8(0) DOT8(1) DOT8(2) DOT8(3) DOT8(4) DOT8(5) DOT8(6) DOT8(7)       \
    const float ar = (sr0 + sr1) + br + p##u##r;                          \
    const float az = (sz0 + sz1) + bz + p##u##z;                          \
    const float ghn = (sn0 + sn1) + bhn;                                  \
    const float rr = frcp(1.f + ex2(ar * -LOG2E));                        \
    const float zz = frcp(1.f + ex2(az * -LOG2E));                        \
    const float nx = (p##u##n + bn) + rr * ghn;                           \
    const float th = 1.f - 2.f * frcp(1.f + ex2(nx * (2.f * LOG2E)));     \
    const float hn = th + zz * (hself - th);                              \
    hself = hn;                                                           \
    hl[g] = (_Float16)hn;                                                 \
    xptr[(size_t)(t + (u)) * HD] = f2bf(hn);                              \
    const float* rw_ = W_ih + (size_t)sidx_ * 192;                        \
    p##u##r = rw_[g]; p##u##z = rw_[64 + g]; p##u##n = rw_[128 + g]; }

  const int ngroups = (nst + 3) >> 2;
  for (int tg = 0; tg < ngroups; ++tg) {
    const int t = tg * 4;
    GSTEP(0)
    GSTEP(1)
    GSTEP(2)
    GSTEP(3)
  }
#undef GSTEP

  // zero-fill padded rows (overwrites the <=3 garbage tail stores too;
  // ws is re-poisoned before every call)
  for (int i = nst * HD + g; i < LMAXT * HD; i += 64)
    Xb[(size_t)b * (LMAXT * HD) + i] = 0;
}

// ---------------------------------------------------------------------------
// Kernel C: MFMA bf16 fused projection + logsumexp + NLL.
// Block = 512 threads = 8 waves sharing one (b, 32-row chunk); waves split
// the 257 column tiles (33 each -> 66 KB Wb stream per wave). Partial exp
// sums merge via LDS. Grid 640 blocks -> 20 waves/CU.
// ---------------------------------------------------------------------------
__global__ __launch_bounds__(512) void k_proj(
    const unsigned short* __restrict__ Xb,
    const unsigned short* __restrict__ Wb,
    const float* __restrict__ bo2,
    const int* __restrict__ seq, const int* __restrict__ steps,
    const float* __restrict__ b_out,
    float* __restrict__ loss_accum) {
  const int l  = threadIdx.x & 63;
  const int wv = threadIdx.x >> 6;         // 0..7 column-split wave id
  const int b  = blockIdx.x / 10;
  const int t0 = (blockIdx.x % 10) * 32;
  const int nst = steps[b];
  const bool active = (t0 < nst);          // block-uniform

  __shared__ float spart[CSPLIT][32];

  if (active) {
    const int lm = l & 15;
    const int q  = l >> 4;

    const unsigned short* xp0 = Xb + ((size_t)b * LMAXT + t0 + lm) * HD + q * 8;
    const bf16x8 a00 = ldb8(xp0);
    const bf16x8 a01 = ldb8(xp0 + 32);
    const bf16x8 a10 = ldb8(xp0 + 16 * HD);
    const bf16x8 a11 = ldb8(xp0 + 16 * HD + 32);

    float s[8];
#pragma unroll
    for (int i = 0; i < 8; ++i) s[i] = 0.f;

    const int ct0 = wv * 33;
    const int ct1 = (ct0 + 33 < NTILE) ? (ct0 + 33) : NTILE;   // wave 7: 26

    const unsigned short* wp = Wb + lm * 64 + q * 8;
    const float* bop = bo2 + lm;

    bf16x8 b0 = ldb8(wp + (size_t)ct0 * 1024);
    bf16x8 b1 = ldb8(wp + (size_t)ct0 * 1024 + 32);
    float  bo = bop[ct0 * 16];
    for (int ct = ct0; ct < ct1; ++ct) {
      bf16x8 nb0, nb1; float nbo;
      if (ct + 1 < ct1) {
        const unsigned short* wpn = wp + (size_t)(ct + 1) * 1024;
        nb0 = ldb8(wpn); nb1 = ldb8(wpn + 32); nbo = bop[(ct + 1) * 16];
      }
      f32x4 acc0 = {0.f, 0.f, 0.f, 0.f};
      f32x4 acc1 = {0.f, 0.f, 0.f, 0.f};
      acc0 = __builtin_amdgcn_mfma_f32_16x16x32_bf16(a00, b0, acc0, 0, 0, 0);
      acc0 = __builtin_amdgcn_mfma_f32_16x16x32_bf16(a01, b1, acc0, 0, 0, 0);
      acc1 = __builtin_amdgcn_mfma_f32_16x16x32_bf16(a10, b0, acc1, 0, 0, 0);
      acc1 = __builtin_amdgcn_mfma_f32_16x16x32_bf16(a11, b1, acc1, 0, 0, 0);
#pragma unroll
      for (int i = 0; i < 4; ++i) {
        s[i]     += ex2(fmaf(acc0[i], LOG2E, bo));
        s[4 + i] += ex2(fmaf(acc1[i], LOG2E, bo));
      }
      if (ct + 1 < ct1) { b0 = nb0; b1 = nb1; bo = nbo; }
    }

    // reduce across the 16 lanes (lm) sharing each row
#pragma unroll
    for (int m = 1; m < 16; m <<= 1) {
#pragma unroll
      for (int i = 0; i < 8; ++i) s[i] += __shfl_xor(s[i], m, 64);
    }
    // D-layout: lane q*16 holds rows q*4+i (tile0) / 16+q*4+i (tile1)
    if (lm == 0) {
#pragma unroll
      for (int i = 0; i < 4; ++i) {
        spart[wv][q * 4 + i]      = s[i];
        spart[wv][16 + q * 4 + i] = s[4 + i];
      }
    }
  }
  __syncthreads();

  float nll = 0.f;
  if (active && threadIdx.x < 32) {
    const int t = t0 + threadIdx.x;
    if (t < nst) {
      float ssum = 0.f;
#pragma unroll
      for (int c = 0; c < CSPLIT; ++c) ssum += spart[c][threadIdx.x];
      const int col = seq[b * SEQ_STRIDE + t + 1];
      // target logit from the SAME bf16 operands (consistent cancellation)
      const unsigned short* xr = Xb + ((size_t)b * LMAXT + t) * HD;
      const unsigned short* wc = Wb + (size_t)(col >> 4) * 1024 + (col & 15) * 64;
      float tl = b_out[col];
#pragma unroll 16
      for (int k = 0; k < 64; ++k)
        tl = fmaf(bf2f(xr[k]), bf2f(wc[k]), tl);
      nll = (30.f + __logf(ssum)) - tl;
    }
  }
  if (threadIdx.x < 64) {
#pragma unroll
    for (int off = 32; off; off >>= 1) nll += __shfl_down(nll, off, 64);
    if (threadIdx.x == 0) atomicAdd(loss_accum, nll);
  }
}

// ---------------------------------------------------------------------------
// Kernel D: finalize (loss_sum / count).
// ---------------------------------------------------------------------------
__global__ void k_final(const float* __restrict__ loss_accum,
                        const int* __restrict__ steps,
                        float* __restrict__ out) {
  if (threadIdx.x == 0 && blockIdx.x == 0) {
    int cnt = 0;
    for (int i = 0; i < NB; ++i) cnt += steps[i];
    out[0] = loss_accum[0] / (float)cnt;
  }
}

// ---------------------------------------------------------------------------
extern "C" void kernel_launch(void* const* d_in, const int* in_sizes, int n_in,
                              void* d_out, int out_size, void* d_ws,
                              size_t ws_size, hipStream_t stream) {
  const float* embeds  = (const float*)d_in[0];
  const float* true_fp = (const float*)d_in[1];
  const int*   perm    = (const int*)d_in[5];
  const float* W_ih    = (const float*)d_in[6];
  const float* b_ih    = (const float*)d_in[7];
  const float* W_hh    = (const float*)d_in[8];
  const float* b_hh    = (const float*)d_in[9];
  const float* W_out   = (const float*)d_in[10];
  const float* b_out   = (const float*)d_in[11];

  char*  ws     = (char*)d_ws;
  int*   seq    = (int*)(ws + SEQ_OFF);
  int*   steps  = (int*)(ws + STEPS_OFF);
  float* loss   = (float*)(ws + LOSS_OFF);
  unsigned short* Xb = (unsigned short*)(ws + XB_OFF);
  unsigned short* Wb = (unsigned short*)(ws + WB_OFF);
  float* bo2    = (float*)(ws + BO_OFF);
  float* out    = (float*)d_out;

  k_setup<<<NB, 64, 0, stream>>>(true_fp, perm, seq, steps, loss);
  k_prep<<<NTILE, 256, 0, stream>>>(W_out, b_out, Wb, bo2);
  k_gru<<<NB, 64, 0, stream>>>(embeds, W_ih, b_ih, W_hh, b_hh, seq, steps, Xb);
  k_proj<<<640, 512, 0, stream>>>(Xb, Wb, bo2, seq, steps, b_out, loss);
  k_final<<<1, 64, 0, stream>>>(loss, steps, out);
}